// Round 11
// baseline (219.237 us; speedup 1.0000x reference)
//
#include <hip/hip_runtime.h>
#include <cstdint>
#include <cstddef>

#define BATCH   16384
#define N_IN    128
#define CTX     128
#define HDIM    1024
#define NB      8
#define OUT_MULT 23                 // 3*NB-1 (logical)
#define OUT_PAD 24                  // padded per-group width (col 23 = zeros)
#define NOUTP   (N_IN * OUT_PAD)    // 3072
#define KCAT    (CTX + N_IN)        // 256

typedef __bf16 bf16x8 __attribute__((ext_vector_type(8)));
typedef float  f32x4  __attribute__((ext_vector_type(4)));

__device__ __forceinline__ uint16_t f2bf(float f) {
    union { float f; uint32_t u; } v; v.f = f;
    uint32_t u = v.u;
    u += 0x7FFFu + ((u >> 16) & 1u);   // RNE
    return (uint16_t)(u >> 16);
}

// ---- degree-sorted permutation of the hidden dim ---------------------------
__device__ __forceinline__ int kpref_dev(int d) {
    return (d <= 8) ? 9 * d : 72 + 8 * (d - 8);
}
__device__ __forceinline__ int dpos_dev(int p) {
    return (p < 72) ? (p / 9) : (8 + ((p - 72) >> 3));
}
__device__ __forceinline__ int h_of(int p) {
    if (p < 72) { int d = p / 9, j = p - 9 * d; return d + 127 * j; }
    int q = p - 72; int d = 8 + (q >> 3); int j = q & 7; return d + 127 * j;
}

// async global->LDS, 16B per lane; LDS dest = wave-uniform base + lane*16,
// global side is a per-lane address (gather is allowed).
__device__ __forceinline__ void async_ld16(const void* g, const void* l) {
    __builtin_amdgcn_global_load_lds(
        (__attribute__((address_space(1))) void*)(uintptr_t)g,
        (__attribute__((address_space(3))) void*)(uint32_t)(uintptr_t)l,
        16, 0, 0);
}

// ---------------- one fused pack kernel (coalesced; verified) ---------------

__global__ void pack_all(
    const float* __restrict__ x,    const float* __restrict__ ctx,
    const float* __restrict__ ctx_w,const float* __restrict__ w0,
    const float* __restrict__ b0,   const float* __restrict__ w1,
    const float* __restrict__ b1,   const float* __restrict__ w2,
    const float* __restrict__ b2,
    uint16_t* __restrict__ xcat, uint16_t* __restrict__ wcat,
    uint16_t* __restrict__ w1m,  uint16_t* __restrict__ w2p,
    float* __restrict__ b0p, float* __restrict__ b1p, float* __restrict__ b2p,
    float* __restrict__ ldz)
{
    __shared__ float srow[HDIM];             // 4 KB staging for permuted packs
    const int blk = blockIdx.x;
    const int tid = threadIdx.x;

    if (blk < 4096) {                        // xcat: BATCH x KCAT, 4 elem/thread
        int idx4 = (blk * 256 + tid) * 4;
        int b = idx4 >> 8, c = idx4 & 255;
        f32x4 v = (c < CTX) ? *(const f32x4*)(ctx + (b << 7) + c)
                            : *(const f32x4*)(x   + (b << 7) + (c - CTX));
        ushort4 o;
        o.x = f2bf(v[0]); o.y = f2bf(v[1]); o.z = f2bf(v[2]); o.w = f2bf(v[3]);
        *(ushort4*)(xcat + idx4) = o;
    } else if (blk < 5120) {                 // wcat: HDIM x KCAT, rows sorted
        int idx = (blk - 4096) * 256 + tid;
        int p = idx >> 8, c = idx & 255;
        int h = h_of(p);
        float v;
        if (c < CTX) v = ctx_w[(h << 7) + c];
        else {
            int col = c - CTX;               // mask0: dpos(p) >= col
            v = (dpos_dev(p) >= col) ? w0[(h << 7) + col] : 0.0f;
        }
        wcat[idx] = f2bf(v);
    } else if (blk < 6144) {                 // w1m: one dest row per block
        const int po = blk - 5120;
        const int drow = dpos_dev(po);
        const float* src = w1 + (size_t)h_of(po) * HDIM;
        *((f32x4*)srow + tid) = *((const f32x4*)src + tid);   // 1024 floats
        __syncthreads();
        ushort4 o;
#pragma unroll
        for (int e = 0; e < 4; ++e) {
            int pi = 4 * tid + e;
            float v = (drow >= dpos_dev(pi)) ? srow[h_of(pi)] : 0.0f;
            ((uint16_t*)&o)[e] = f2bf(v);
        }
        *((ushort4*)(w1m + (size_t)po * HDIM) + tid) = o;
    } else if (blk < 9216) {                 // w2p: one dest row per block
        const int oo = blk - 6144;           // 0..3071
        const int g = oo / OUT_PAD, t = oo - g * OUT_PAD;
        const bool live = (t < OUT_MULT);    // block-uniform branch
        if (live) {
            const float* src = w2 + (size_t)(g * OUT_MULT + t) * HDIM;
            *((f32x4*)srow + tid) = *((const f32x4*)src + tid);
        }
        __syncthreads();
        ushort4 o;
#pragma unroll
        for (int e = 0; e < 4; ++e) {
            int pi = 4 * tid + e;
            float v = (live && g > dpos_dev(pi)) ? srow[h_of(pi)] : 0.0f;
            ((uint16_t*)&o)[e] = f2bf(v);
        }
        *((ushort4*)(w2p + (size_t)oo * HDIM) + tid) = o;
    } else if (blk < 9232) {                 // biases
        int idx = (blk - 9216) * 256 + tid;  // 0..4095
        if (idx < HDIM) {
            int h = h_of(idx);
            b0p[idx] = b0[h];
            b1p[idx] = b1[h];
        } else {
            int oo = idx - HDIM;             // 0..3071
            int g = oo / OUT_PAD, t = oo - g * OUT_PAD;
            b2p[oo] = (t < OUT_MULT) ? b2[g * OUT_MULT + t] : 0.0f;
        }
    } else {                                 // zero ldsum (BATCH floats)
        int idx = (blk - 9232) * 256 + tid;
        ldz[idx] = 0.0f;
    }
}

// ---------------- bf16 GEMM body, C = A @ B^T + bias (relu, bf16 out) -------
// R11: WIDE 128 M x 256 N tile (waves 2x2: 64 x 128, acc 4x8 -> 128 AGPR).
// Rationale (stage-bytes model, validated R1->R6 on g3): 128-wide tiles
// stage 32 KB per 32-MFMA iter = 2x g3's stage-per-FLOP. 256-wide:
// g2 block-iters 9216->5120 (-44%), staged bytes -17%; g1 iters -46%.
// Single-buffered R1-form 2-barrier loop (dbuf at 96 KB LDS would force
// 1 blk/CU -- R5 lesson). LDS 48 KB -> 2 blocks/CU at (256,2); grid 512
// blocks = fully resident, no tail. Combined regs ~228 < 256: no R9 spill.
// BK=64, XOR-swizzled LDS (conflict-free ds_read_b128), K prefix by MODE.
// nt flipped: heavy-K tiles launch first.

template<int MODE>
__device__ __forceinline__ void gemm_bt_body(
    const uint16_t* __restrict__ A,
    const uint16_t* __restrict__ B,
    const float*    __restrict__ bias,
    uint16_t*       __restrict__ C,
    int N, int K, int NT)
{
    __shared__ __align__(16) uint16_t sA[128 * 64];   // 16 KB
    __shared__ __align__(16) uint16_t sB[256 * 64];   // 32 KB

    const int GM    = 64;
    const int per   = GM * NT;
    const int id    = blockIdx.x;
    const int grp   = id / per;
    const int rem   = id - grp * per;
    const int mt    = grp * GM + (rem & (GM - 1));
    const int nt    = (NT - 1) - (rem >> 6);          // heavy tiles first
    const int bm    = mt << 7;
    const int bn    = nt << 8;                        // 256-wide

    int K_eff;
    if (MODE == 0)      { int dmax = dpos_dev(bn + 255); K_eff = 128 + dmax + 1; }
    else                { int dmax = dpos_dev(bn + 255); K_eff = kpref_dev(dmax + 1); }
    K_eff = min(K, (K_eff + 63) & ~63);

    const int tid   = threadIdx.x;
    const int wid   = tid >> 6;
    const int lane  = tid & 63;
    const int wm    = (wid & 1) << 6;                 // 0 / 64
    const int wn    = (wid >> 1) << 7;                // 0 / 128
    const int lrow  = lane & 15;
    const int lquad = lane >> 4;

    const f32x4 vzero = {0.0f, 0.0f, 0.0f, 0.0f};
    f32x4 acc[4][8];
#pragma unroll
    for (int i = 0; i < 4; ++i)
#pragma unroll
        for (int j = 0; j < 8; ++j) acc[i][j] = vzero;

    int goffA[4], goffB[8];
#pragma unroll
    for (int t = 0; t < 4; ++t) {
        int c = t * 256 + tid;
        int row = c >> 3, j = c & 7;                  // rows 0..127
        goffA[t] = row * K * 2 + (j ^ (row & 7)) * 16;
    }
#pragma unroll
    for (int t = 0; t < 8; ++t) {
        int c = t * 256 + tid;
        int row = c >> 3, j = c & 7;                  // rows 0..255
        goffB[t] = row * K * 2 + (j ^ (row & 7)) * 16;
    }
    const char* gA = (const char*)(A + (size_t)bm * K);
    const char* gB = (const char*)(B + (size_t)bn * K);

    const int octx = lrow & 7;
    const uint16_t* rA = sA + (wm + lrow) * 64;
    const uint16_t* rB = sB + (wn + lrow) * 64;

    for (int k0 = 0; k0 < K_eff; k0 += 64) {
        __syncthreads();
        const int kb = k0 * 2;
#pragma unroll
        for (int t = 0; t < 8; ++t) {
            const int ldsoff = (t * 256 + (wid << 6)) * 16;   // wave-uniform
            if (t < 4)
                async_ld16(gA + goffA[t] + kb, (const char*)sA + ldsoff);
            async_ld16(gB + goffB[t] + kb, (const char*)sB + ldsoff);
        }
        __syncthreads();

#pragma unroll
        for (int ks = 0; ks < 2; ++ks) {
            const int oct = ((ks << 2) | lquad) ^ octx;
            bf16x8 af[4], bfr[8];
#pragma unroll
            for (int i = 0; i < 4; ++i) af[i]  = *(const bf16x8*)(rA + i * 1024 + oct * 8);
#pragma unroll
            for (int j = 0; j < 8; ++j) bfr[j] = *(const bf16x8*)(rB + j * 1024 + oct * 8);
#pragma unroll
            for (int i = 0; i < 4; ++i)
#pragma unroll
                for (int j = 0; j < 8; ++j)
                    acc[i][j] = __builtin_amdgcn_mfma_f32_16x16x32_bf16(
                                    af[i], bfr[j], acc[i][j], 0, 0, 0);
        }
    }

#pragma unroll
    for (int j = 0; j < 8; ++j) {
        const int col = bn + wn + j * 16 + lrow;
        const float bv = bias[col];
#pragma unroll
        for (int i = 0; i < 4; ++i) {
            const int row0 = bm + wm + i * 16 + (lquad << 2);
#pragma unroll
            for (int r = 0; r < 4; ++r) {
                float v = fmaxf(acc[i][j][r] + bv, 0.0f);
                C[(size_t)(row0 + r) * N + col] = f2bf(v);
            }
        }
    }
}

__global__ __launch_bounds__(256, 2) void gemm1_k(
    const uint16_t* __restrict__ A, const uint16_t* __restrict__ B,
    const float* __restrict__ bias, uint16_t* __restrict__ C,
    int N, int K, int NT)
{ gemm_bt_body<0>(A, B, bias, C, N, K, NT); }

__global__ __launch_bounds__(256, 2) void gemm2_k(
    const uint16_t* __restrict__ A, const uint16_t* __restrict__ B,
    const float* __restrict__ bias, uint16_t* __restrict__ C,
    int N, int K, int NT)
{ gemm_bt_body<1>(A, B, bias, C, N, K, NT); }

// ---------------- spline evaluation (VERBATIM known-good math) --------------
// NOTE: the trans-op diet (Taylor softmax exp + fused log) failed absmax=0.75
// in earlier rounds despite airtight algebra -- unresolved. Do NOT touch.
// p-loads vectorized to 6x ds_read_b128 (verified identical since R2).

__device__ __forceinline__ float frcp(float v) { return __builtin_amdgcn_rcpf(v); }
__device__ __forceinline__ float softplusf(float v) {
    return fmaxf(v, 0.0f) + __logf(1.0f + __expf(-fabsf(v)));
}

__device__ __forceinline__ void spline_eval(const float* __restrict__ pp,
                                            float xv, float& yout, float& ldout)
{
    float p[OUT_PAD];
#pragma unroll
    for (int k = 0; k < OUT_PAD / 4; ++k)
        *(f32x4*)(p + 4 * k) = *(const f32x4*)(pp + 4 * k);

    const float TAILF = 3.0f;
    const float MIN_W = 0.001f, MIN_H = 0.001f, MIN_D = 0.001f;
    const float INV_SCALE = 1.0f / 724.0773439350246f;   // 1/sqrt(H*H/2)

    const float xc = fminf(fmaxf(xv, -TAILF), TAILF);

    float uw[NB], uh[NB];
#pragma unroll
    for (int k = 0; k < NB; ++k) { uw[k] = p[k] * INV_SCALE; uh[k] = p[NB + k] * INV_SCALE; }
    float mw = uw[0], mh = uh[0];
#pragma unroll
    for (int k = 1; k < NB; ++k) { mw = fmaxf(mw, uw[k]); mh = fmaxf(mh, uh[k]); }
    float ew[NB], eh[NB], sw = 0.0f, sh = 0.0f;
#pragma unroll
    for (int k = 0; k < NB; ++k) {
        ew[k] = __expf(uw[k] - mw); sw += ew[k];
        eh[k] = __expf(uh[k] - mh); sh += eh[k];
    }
    const float FACW = (1.0f - MIN_W * NB) * frcp(sw);
    const float FACH = (1.0f - MIN_H * NB) * frcp(sh);

    float cw[NB + 1], ch[NB + 1];
    cw[0] = -TAILF; ch[0] = -TAILF;
    float aw = 0.0f, ah = 0.0f;
#pragma unroll
    for (int k = 0; k < NB; ++k) {
        aw += MIN_W + FACW * ew[k];
        ah += MIN_H + FACH * eh[k];
        cw[k + 1] = (k == NB - 1) ? TAILF : 2.0f * TAILF * aw - TAILF;
        ch[k + 1] = (k == NB - 1) ? TAILF : 2.0f * TAILF * ah - TAILF;
    }

    float dd[NB + 1];
    dd[0]  = 1.0f;   // MIN_D + softplus(DPAD) == 1 exactly by construction
    dd[NB] = 1.0f;
#pragma unroll
    for (int k = 1; k < NB; ++k) dd[k] = MIN_D + softplusf(p[2 * NB + (k - 1)]);

    float in_cw = cw[0], cw_n = cw[1], in_ch = ch[0], ch_n = ch[1];
    float d0 = dd[0], d1 = dd[1];
#pragma unroll
    for (int k = 1; k < NB; ++k) {
        const bool ge = (xc >= cw[k]);
        in_cw = ge ? cw[k]     : in_cw;
        cw_n  = ge ? cw[k + 1] : cw_n;
        in_ch = ge ? ch[k]     : in_ch;
        ch_n  = ge ? ch[k + 1] : ch_n;
        d0    = ge ? dd[k]     : d0;
        d1    = ge ? dd[k + 1] : d1;
    }
    const float in_w  = cw_n - in_cw;
    const float in_h  = ch_n - in_ch;
    const float inv_w = frcp(in_w);
    const float delta = in_h * inv_w;
    const float theta = (xc - in_cw) * inv_w;
    const float omt   = 1.0f - theta;
    const float t1m   = theta * omt;
    const float denom = delta + (d0 + d1 - 2.0f * delta) * t1m;
    const float num   = in_h * (delta * theta * theta + d0 * t1m);
    float yv = in_ch + num * frcp(denom);
    float ld = 2.0f * __logf(delta)
             + __logf(d1 * theta * theta + 2.0f * delta * t1m + d0 * omt * omt)
             - 2.0f * __logf(denom);
    const bool inside = fabsf(xv) <= TAILF;
    yout  = inside ? yv : xv;
    ldout = inside ? ld : 0.0f;
}

// ---------------- fused GEMM3 + spline (R10 VERBATIM: measured best) --------
// Wide 128 M x 192 N tile (waves 2x2 of 64x96, acc 4x6), single-buffered
// 2-barrier loop, no swizzle, 4-phase epilogue, __launch_bounds__(256,2).
// R9 LESSON: launch_bounds caps the UNIFIED VGPR+AGPR file; (256,4) spilled
// the 96-reg acc. Keep (256,2). K_eff = 64*(nt+1) exact. 78.2us measured.

__global__ __launch_bounds__(256, 2) void gemm3_spline(
    const uint16_t* __restrict__ A,      // h2: BATCH x HDIM (sorted K)
    const uint16_t* __restrict__ B,      // w2p: NOUTP x HDIM
    const float*    __restrict__ bias,   // b2p: NOUTP
    const float*    __restrict__ x,      // BATCH x N_IN
    float* __restrict__ y,
    float* __restrict__ ldsum)
{
    __shared__ __align__(16) char smem[40960];      // sA 16384 | sB 24576
    uint16_t* sA = (uint16_t*)smem;
    uint16_t* sB = (uint16_t*)(smem + 16384);
    float* ep    = (float*)smem;                    // 32*196*4 = 25088 (alias)

    const int NT  = 16;                             // 3072 / 192
    const int per = 64 * NT;                        // 1024
    const int id  = blockIdx.x;                     // 0..2047
    const int grp = id / per;
    const int rem = id - grp * per;
    const int mt  = grp * 64 + (rem & 63);
    const int nt  = (NT - 1) - (rem >> 6);          // heavy tiles first
    const int bm  = mt << 7;
    const int bn  = nt * 192;

    const int K = HDIM;
    int K_eff = kpref_dev(8 * nt + 7);              // = 64*(nt+1), exact
    K_eff = min(K, (K_eff + 63) & ~63);

    const int tid   = threadIdx.x;
    const int wid   = tid >> 6;
    const int lane  = tid & 63;
    const int wm    = (wid & 1) << 6;               // 0 / 64
    const int wn    = (wid >> 1) * 96;              // 0 / 96
    const int lrow  = lane & 15;
    const int lquad = lane >> 4;

    const f32x4 vzero = {0.0f, 0.0f, 0.0f, 0.0f};
    f32x4 acc[4][6];
#pragma unroll
    for (int i = 0; i < 4; ++i)
#pragma unroll
        for (int j = 0; j < 6; ++j) acc[i][j] = vzero;

    int goffA[4], goffB[6];
#pragma unroll
    for (int t = 0; t < 4; ++t) {
        int c = t * 256 + tid;
        int row = c >> 3, j = c & 7;                // row 0..127
        goffA[t] = row * K * 2 + (j ^ (row & 7)) * 16;
    }
#pragma unroll
    for (int t = 0; t < 6; ++t) {
        int c = t * 256 + tid;
        int row = c >> 3, j = c & 7;                // row 0..191
        goffB[t] = row * K * 2 + (j ^ (row & 7)) * 16;
    }
    const char* gA = (const char*)(A + (size_t)bm * K);
    const char* gB = (const char*)(B + (size_t)bn * K);

    const int octx = lrow & 7;
    const uint16_t* rA = sA + (wm + lrow) * 64;
    const uint16_t* rB = sB + (wn + lrow) * 64;

    for (int k0 = 0; k0 < K_eff; k0 += 64) {
        __syncthreads();
        const int kb = k0 * 2;
#pragma unroll
        for (int t = 0; t < 6; ++t) {
            const int ldsoff = (t * 256 + (wid << 6)) * 16;   // wave-uniform
            if (t < 4)
                async_ld16(gA + goffA[t] + kb, (const char*)sA + ldsoff);
            async_ld16(gB + goffB[t] + kb, (const char*)sB + ldsoff);
        }
        __syncthreads();

#pragma unroll
        for (int ks = 0; ks < 2; ++ks) {
            const int oct = ((ks << 2) | lquad) ^ octx;
            bf16x8 af[4], bfr[6];
#pragma unroll
            for (int i = 0; i < 4; ++i) af[i]  = *(const bf16x8*)(rA + i * 1024 + oct * 8);
#pragma unroll
            for (int j = 0; j < 6; ++j) bfr[j] = *(const bf16x8*)(rB + j * 1024 + oct * 8);
#pragma unroll
            for (int i = 0; i < 4; ++i)
#pragma unroll
                for (int j = 0; j < 6; ++j)
                    acc[i][j] = __builtin_amdgcn_mfma_f32_16x16x32_bf16(
                                    af[i], bfr[j], acc[i][j], 0, 0, 0);
        }
    }

    __syncthreads();                    // staging consumers done; reuse as ep

    // ---- FOUR-PHASE epilogue: 32 rows each --------------------------------
#pragma unroll
    for (int ph = 0; ph < 4; ++ph) {
        if ((wid & 1) == (ph >> 1)) {   // waves owning this 64-row half
#pragma unroll
            for (int ii = 0; ii < 2; ++ii) {
                const int i  = ((ph & 1) << 1) + ii;        // acc row-band
                const int l0 = (ii << 4) + (lquad << 2);    // local row 0..31
#pragma unroll
                for (int j = 0; j < 6; ++j) {
                    const int col = wn + j * 16 + lrow;     // 0..191
                    const float bv = bias[bn + col];
#pragma unroll
                    for (int r = 0; r < 4; ++r)
                        ep[(l0 + r) * 196 + col] = acc[i][j][r] + bv;
                }
            }
        }
        __syncthreads();

        // 256 spline evals: one per thread (32 rows x 8 groups)
        {
            const int row  = tid >> 3;          // 0..31
            const int sg   = tid & 7;           // group within tile (0..7)
            const int grow = bm + (ph << 5) + row;
            const float xv = x[(size_t)grow * N_IN + (8 * nt + sg)];
            float yv, ld;
            spline_eval(ep + row * 196 + sg * OUT_PAD, xv, yv, ld);
            y[(size_t)grow * N_IN + 8 * nt + sg] = yv;

            // sum ld over the 8 lanes sharing this row
            ld += __shfl_xor(ld, 1, 64);
            ld += __shfl_xor(ld, 2, 64);
            ld += __shfl_xor(ld, 4, 64);
            if (sg == 0) atomicAdd(&ldsum[grow], ld);
        }
        if (ph < 3) __syncthreads();    // next phase's writes clobber ep
    }
}

// ---------------- host orchestration ----------------------------------------

extern "C" void kernel_launch(void* const* d_in, const int* in_sizes, int n_in,
                              void* d_out, int out_size, void* d_ws, size_t ws_size,
                              hipStream_t stream)
{
    const float* x     = (const float*)d_in[0];
    const float* ctx   = (const float*)d_in[1];
    const float* ctx_w = (const float*)d_in[2];
    const float* w0    = (const float*)d_in[3];
    const float* b0    = (const float*)d_in[4];
    const float* w1    = (const float*)d_in[5];
    const float* b1    = (const float*)d_in[6];
    const float* w2    = (const float*)d_in[7];
    const float* b2    = (const float*)d_in[8];
    // d_in[9..11] = masks: unused (computed analytically from indices)

    char* ws = (char*)d_ws;
    const size_t XCAT_B = (size_t)BATCH * KCAT * 2;   //   8 MB
    const size_t H_B    = (size_t)BATCH * HDIM * 2;   //  32 MB each
    const size_t WCAT_B = (size_t)HDIM * KCAT * 2;
    const size_t W1_B   = (size_t)HDIM * HDIM * 2;
    const size_t W2P_B  = (size_t)NOUTP * HDIM * 2;

    uint16_t* xcat = (uint16_t*)(ws);
    uint16_t* h1   = (uint16_t*)(ws + XCAT_B);
    uint16_t* h2   = (uint16_t*)(ws + XCAT_B + H_B);
    uint16_t* wcat = (uint16_t*)(ws + XCAT_B + 2 * H_B);
    uint16_t* w1m  = (uint16_t*)(ws + XCAT_B + 2 * H_B + WCAT_B);
    uint16_t* w2p  = (uint16_t*)(ws + XCAT_B + 2 * H_B + WCAT_B + W1_B);
    float*    b0p  = (float*)   (ws + XCAT_B + 2 * H_B + WCAT_B + W1_B + W2P_B);
    float*    b1p  = b0p + HDIM;
    float*    b2p  = b1p + HDIM;

    float* yout  = (float*)d_out;
    float* ldout = yout + (size_t)BATCH * N_IN;

    pack_all<<<9296, 256, 0, stream>>>(x, ctx, ctx_w, w0, b0, w1, b1, w2, b2,
                                       xcat, wcat, w1m, w2p, b0p, b1p, b2p,
                                       ldout);

    const dim3 blk(256);
    // 256-wide N tiles: grid = 128 mt x (HDIM/256) nt = 512 blocks each
    gemm1_k<<<dim3(128 * (HDIM / 256)), blk, 0, stream>>>(
        xcat, wcat, b0p, h1, HDIM, KCAT, HDIM / 256);
    gemm2_k<<<dim3(128 * (HDIM / 256)), blk, 0, stream>>>(
        h1, w1m, b1p, h2, HDIM, HDIM, HDIM / 256);
    gemm3_spline<<<dim3(128 * 16), blk, 0, stream>>>(
        h2, w2p, b2p, x, yout, ldout);
}

// Round 12
// 210.534 us; speedup vs baseline: 1.0413x; 1.0413x over previous
//
#include <hip/hip_runtime.h>
#include <cstdint>
#include <cstddef>

#define BATCH   16384
#define N_IN    128
#define CTX     128
#define HDIM    1024
#define NB      8
#define OUT_MULT 23                 // 3*NB-1 (logical)
#define OUT_PAD 24                  // padded per-group width (col 23 = zeros)
#define NOUTP   (N_IN * OUT_PAD)    // 3072
#define KCAT    (CTX + N_IN)        // 256

typedef __bf16 bf16x8 __attribute__((ext_vector_type(8)));
typedef float  f32x4  __attribute__((ext_vector_type(4)));

__device__ __forceinline__ uint16_t f2bf(float f) {
    union { float f; uint32_t u; } v; v.f = f;
    uint32_t u = v.u;
    u += 0x7FFFu + ((u >> 16) & 1u);   // RNE
    return (uint16_t)(u >> 16);
}

// ---- degree-sorted permutation of the hidden dim ---------------------------
__device__ __forceinline__ int kpref_dev(int d) {
    return (d <= 8) ? 9 * d : 72 + 8 * (d - 8);
}
__device__ __forceinline__ int dpos_dev(int p) {
    return (p < 72) ? (p / 9) : (8 + ((p - 72) >> 3));
}
__device__ __forceinline__ int h_of(int p) {
    if (p < 72) { int d = p / 9, j = p - 9 * d; return d + 127 * j; }
    int q = p - 72; int d = 8 + (q >> 3); int j = q & 7; return d + 127 * j;
}

// async global->LDS, 16B per lane; LDS dest = wave-uniform base + lane*16,
// global side is a per-lane address (gather is allowed).
__device__ __forceinline__ void async_ld16(const void* g, const void* l) {
    __builtin_amdgcn_global_load_lds(
        (__attribute__((address_space(1))) void*)(uintptr_t)g,
        (__attribute__((address_space(3))) void*)(uint32_t)(uintptr_t)l,
        16, 0, 0);
}

// ---------------- one fused pack kernel (coalesced; verified) ---------------

__global__ void pack_all(
    const float* __restrict__ x,    const float* __restrict__ ctx,
    const float* __restrict__ ctx_w,const float* __restrict__ w0,
    const float* __restrict__ b0,   const float* __restrict__ w1,
    const float* __restrict__ b1,   const float* __restrict__ w2,
    const float* __restrict__ b2,
    uint16_t* __restrict__ xcat, uint16_t* __restrict__ wcat,
    uint16_t* __restrict__ w1m,  uint16_t* __restrict__ w2p,
    float* __restrict__ b0p, float* __restrict__ b1p, float* __restrict__ b2p,
    float* __restrict__ ldz)
{
    __shared__ float srow[HDIM];             // 4 KB staging for permuted packs
    const int blk = blockIdx.x;
    const int tid = threadIdx.x;

    if (blk < 4096) {                        // xcat: BATCH x KCAT, 4 elem/thread
        int idx4 = (blk * 256 + tid) * 4;
        int b = idx4 >> 8, c = idx4 & 255;
        f32x4 v = (c < CTX) ? *(const f32x4*)(ctx + (b << 7) + c)
                            : *(const f32x4*)(x   + (b << 7) + (c - CTX));
        ushort4 o;
        o.x = f2bf(v[0]); o.y = f2bf(v[1]); o.z = f2bf(v[2]); o.w = f2bf(v[3]);
        *(ushort4*)(xcat + idx4) = o;
    } else if (blk < 5120) {                 // wcat: HDIM x KCAT, rows sorted
        int idx = (blk - 4096) * 256 + tid;
        int p = idx >> 8, c = idx & 255;
        int h = h_of(p);
        float v;
        if (c < CTX) v = ctx_w[(h << 7) + c];
        else {
            int col = c - CTX;               // mask0: dpos(p) >= col
            v = (dpos_dev(p) >= col) ? w0[(h << 7) + col] : 0.0f;
        }
        wcat[idx] = f2bf(v);
    } else if (blk < 6144) {                 // w1m: one dest row per block
        const int po = blk - 5120;
        const int drow = dpos_dev(po);
        const float* src = w1 + (size_t)h_of(po) * HDIM;
        *((f32x4*)srow + tid) = *((const f32x4*)src + tid);   // 1024 floats
        __syncthreads();
        ushort4 o;
#pragma unroll
        for (int e = 0; e < 4; ++e) {
            int pi = 4 * tid + e;
            float v = (drow >= dpos_dev(pi)) ? srow[h_of(pi)] : 0.0f;
            ((uint16_t*)&o)[e] = f2bf(v);
        }
        *((ushort4*)(w1m + (size_t)po * HDIM) + tid) = o;
    } else if (blk < 9216) {                 // w2p: one dest row per block
        const int oo = blk - 6144;           // 0..3071
        const int g = oo / OUT_PAD, t = oo - g * OUT_PAD;
        const bool live = (t < OUT_MULT);    // block-uniform branch
        if (live) {
            const float* src = w2 + (size_t)(g * OUT_MULT + t) * HDIM;
            *((f32x4*)srow + tid) = *((const f32x4*)src + tid);
        }
        __syncthreads();
        ushort4 o;
#pragma unroll
        for (int e = 0; e < 4; ++e) {
            int pi = 4 * tid + e;
            float v = (live && g > dpos_dev(pi)) ? srow[h_of(pi)] : 0.0f;
            ((uint16_t*)&o)[e] = f2bf(v);
        }
        *((ushort4*)(w2p + (size_t)oo * HDIM) + tid) = o;
    } else if (blk < 9232) {                 // biases
        int idx = (blk - 9216) * 256 + tid;  // 0..4095
        if (idx < HDIM) {
            int h = h_of(idx);
            b0p[idx] = b0[h];
            b1p[idx] = b1[h];
        } else {
            int oo = idx - HDIM;             // 0..3071
            int g = oo / OUT_PAD, t = oo - g * OUT_PAD;
            b2p[oo] = (t < OUT_MULT) ? b2[g * OUT_MULT + t] : 0.0f;
        }
    } else {                                 // zero ldsum (BATCH floats)
        int idx = (blk - 9232) * 256 + tid;
        ldz[idx] = 0.0f;
    }
}

// ---------------- bf16 GEMM body (R8 verbatim: counted-vmcnt dbuf) ----------
// Counted-vmcnt double-buffered pipeline (T4): raw s_barrier + vmcnt(8).
// Measured best for g1/g2 (R8/R10 rest-of-total ~130-133us vs 143 with wide
// single-buffered tiles, R11): short-K grids need the pipeline to hide the
// per-iter drain; fixed costs dominate otherwise.
// NOT used for gemm3 (R8: 86us vs 78.2 single-buffered).

template<int MODE>
__device__ __forceinline__ void gemm_bt_body(
    const uint16_t* __restrict__ A,
    const uint16_t* __restrict__ B,
    const float*    __restrict__ bias,
    uint16_t*       __restrict__ C,
    int N, int K, int NT)
{
    __shared__ __align__(16) uint16_t sA[2][128 * 64];   // 32 KB
    __shared__ __align__(16) uint16_t sB[2][128 * 64];   // 32 KB

    const int GM    = 64;
    const int per   = GM * NT;
    const int id    = blockIdx.x;
    const int grp   = id / per;
    const int rem   = id - grp * per;
    const int mt    = grp * GM + (rem & (GM - 1));
    const int nt    = (NT - 1) - (rem >> 6);          // heavy tiles first
    const int bm    = mt << 7;
    const int bn    = nt << 7;

    int K_eff;
    if (MODE == 0)      { int dmax = dpos_dev(bn + 127); K_eff = 128 + dmax + 1; }
    else                { int dmax = dpos_dev(bn + 127); K_eff = kpref_dev(dmax + 1); }
    K_eff = min(K, (K_eff + 63) & ~63);

    const int tid   = threadIdx.x;
    const int wid   = tid >> 6;
    const int lane  = tid & 63;
    const int wm    = (wid & 1) << 6;
    const int wn    = (wid >> 1) << 6;
    const int lrow  = lane & 15;
    const int lquad = lane >> 4;

    const f32x4 vzero = {0.0f, 0.0f, 0.0f, 0.0f};
    f32x4 acc[4][4];
#pragma unroll
    for (int i = 0; i < 4; ++i)
#pragma unroll
        for (int j = 0; j < 4; ++j) acc[i][j] = vzero;

    int goff[4];
#pragma unroll
    for (int t = 0; t < 4; ++t) {
        int c = t * 256 + tid;
        int row = c >> 3, j = c & 7;
        int oct = j ^ (row & 7);
        goff[t] = row * K * 2 + oct * 16;    // bytes
    }
    const char* gA = (const char*)(A + (size_t)bm * K);
    const char* gB = (const char*)(B + (size_t)bn * K);

    const int octx = lrow & 7;

    auto stage = [&](int b, int k0) {         // 8 VMEM instrs per wave
        const int kb = k0 * 2;
#pragma unroll
        for (int t = 0; t < 4; ++t) {
            const int ldsoff = (t * 256 + (wid << 6)) * 16;   // wave-uniform
            async_ld16(gA + goff[t] + kb, (const char*)sA[b] + ldsoff);
            async_ld16(gB + goff[t] + kb, (const char*)sB[b] + ldsoff);
        }
    };

    // prologue: stage tile 0 (stays in flight until the first iter's wait)
    stage(0, 0);

    int cur = 0;
    for (int k0 = 0; k0 < K_eff; k0 += 64) {
        if (k0 + 64 < K_eff) {
            stage(cur ^ 1, k0 + 64);                      // issue-early
            asm volatile("s_waitcnt vmcnt(8)" ::: "memory");  // prev stage done
        } else {
            asm volatile("s_waitcnt vmcnt(0)" ::: "memory");
        }
        __builtin_amdgcn_s_barrier();       // buf[cur] visible to all waves

        const uint16_t* rA = sA[cur] + (wm + lrow) * 64;
        const uint16_t* rB = sB[cur] + (wn + lrow) * 64;
#pragma unroll
        for (int ks = 0; ks < 2; ++ks) {
            const int oct = ((ks << 2) | lquad) ^ octx;
            bf16x8 af[4], bfr[4];
#pragma unroll
            for (int i = 0; i < 4; ++i) af[i]  = *(const bf16x8*)(rA + i * 1024 + oct * 8);
#pragma unroll
            for (int j = 0; j < 4; ++j) bfr[j] = *(const bf16x8*)(rB + j * 1024 + oct * 8);
#pragma unroll
            for (int i = 0; i < 4; ++i)
#pragma unroll
                for (int j = 0; j < 4; ++j)
                    acc[i][j] = __builtin_amdgcn_mfma_f32_16x16x32_bf16(
                                    af[i], bfr[j], acc[i][j], 0, 0, 0);
        }

        __builtin_amdgcn_s_barrier();       // all reads of buf[cur] consumed
        cur ^= 1;
    }

#pragma unroll
    for (int j = 0; j < 4; ++j) {
        const int col = bn + wn + j * 16 + lrow;
        const float bv = bias[col];
#pragma unroll
        for (int i = 0; i < 4; ++i) {
            const int row0 = bm + wm + i * 16 + (lquad << 2);
#pragma unroll
            for (int r = 0; r < 4; ++r) {
                float v = fmaxf(acc[i][j][r] + bv, 0.0f);
                C[(size_t)(row0 + r) * N + col] = f2bf(v);
            }
        }
    }
}

__global__ __launch_bounds__(256, 2) void gemm1_k(
    const uint16_t* __restrict__ A, const uint16_t* __restrict__ B,
    const float* __restrict__ bias, uint16_t* __restrict__ C,
    int N, int K, int NT)
{ gemm_bt_body<0>(A, B, bias, C, N, K, NT); }

__global__ __launch_bounds__(256, 2) void gemm2_k(
    const uint16_t* __restrict__ A, const uint16_t* __restrict__ B,
    const float* __restrict__ bias, uint16_t* __restrict__ C,
    int N, int K, int NT)
{ gemm_bt_body<1>(A, B, bias, C, N, K, NT); }

// ---------------- spline evaluation (VERBATIM known-good math) --------------
// NOTE: the trans-op diet (Taylor softmax exp + fused log) failed absmax=0.75
// in earlier rounds despite airtight algebra -- unresolved. Do NOT touch.
// p-loads vectorized to 6x ds_read_b128 (verified identical since R2).

__device__ __forceinline__ float frcp(float v) { return __builtin_amdgcn_rcpf(v); }
__device__ __forceinline__ float softplusf(float v) {
    return fmaxf(v, 0.0f) + __logf(1.0f + __expf(-fabsf(v)));
}

__device__ __forceinline__ void spline_eval(const float* __restrict__ pp,
                                            float xv, float& yout, float& ldout)
{
    float p[OUT_PAD];
#pragma unroll
    for (int k = 0; k < OUT_PAD / 4; ++k)
        *(f32x4*)(p + 4 * k) = *(const f32x4*)(pp + 4 * k);

    const float TAILF = 3.0f;
    const float MIN_W = 0.001f, MIN_H = 0.001f, MIN_D = 0.001f;
    const float INV_SCALE = 1.0f / 724.0773439350246f;   // 1/sqrt(H*H/2)

    const float xc = fminf(fmaxf(xv, -TAILF), TAILF);

    float uw[NB], uh[NB];
#pragma unroll
    for (int k = 0; k < NB; ++k) { uw[k] = p[k] * INV_SCALE; uh[k] = p[NB + k] * INV_SCALE; }
    float mw = uw[0], mh = uh[0];
#pragma unroll
    for (int k = 1; k < NB; ++k) { mw = fmaxf(mw, uw[k]); mh = fmaxf(mh, uh[k]); }
    float ew[NB], eh[NB], sw = 0.0f, sh = 0.0f;
#pragma unroll
    for (int k = 0; k < NB; ++k) {
        ew[k] = __expf(uw[k] - mw); sw += ew[k];
        eh[k] = __expf(uh[k] - mh); sh += eh[k];
    }
    const float FACW = (1.0f - MIN_W * NB) * frcp(sw);
    const float FACH = (1.0f - MIN_H * NB) * frcp(sh);

    float cw[NB + 1], ch[NB + 1];
    cw[0] = -TAILF; ch[0] = -TAILF;
    float aw = 0.0f, ah = 0.0f;
#pragma unroll
    for (int k = 0; k < NB; ++k) {
        aw += MIN_W + FACW * ew[k];
        ah += MIN_H + FACH * eh[k];
        cw[k + 1] = (k == NB - 1) ? TAILF : 2.0f * TAILF * aw - TAILF;
        ch[k + 1] = (k == NB - 1) ? TAILF : 2.0f * TAILF * ah - TAILF;
    }

    float dd[NB + 1];
    dd[0]  = 1.0f;   // MIN_D + softplus(DPAD) == 1 exactly by construction
    dd[NB] = 1.0f;
#pragma unroll
    for (int k = 1; k < NB; ++k) dd[k] = MIN_D + softplusf(p[2 * NB + (k - 1)]);

    float in_cw = cw[0], cw_n = cw[1], in_ch = ch[0], ch_n = ch[1];
    float d0 = dd[0], d1 = dd[1];
#pragma unroll
    for (int k = 1; k < NB; ++k) {
        const bool ge = (xc >= cw[k]);
        in_cw = ge ? cw[k]     : in_cw;
        cw_n  = ge ? cw[k + 1] : cw_n;
        in_ch = ge ? ch[k]     : in_ch;
        ch_n  = ge ? ch[k + 1] : ch_n;
        d0    = ge ? dd[k]     : d0;
        d1    = ge ? dd[k + 1] : d1;
    }
    const float in_w  = cw_n - in_cw;
    const float in_h  = ch_n - in_ch;
    const float inv_w = frcp(in_w);
    const float delta = in_h * inv_w;
    const float theta = (xc - in_cw) * inv_w;
    const float omt   = 1.0f - theta;
    const float t1m   = theta * omt;
    const float denom = delta + (d0 + d1 - 2.0f * delta) * t1m;
    const float num   = in_h * (delta * theta * theta + d0 * t1m);
    float yv = in_ch + num * frcp(denom);
    float ld = 2.0f * __logf(delta)
             + __logf(d1 * theta * theta + 2.0f * delta * t1m + d0 * omt * omt)
             - 2.0f * __logf(denom);
    const bool inside = fabsf(xv) <= TAILF;
    yout  = inside ? yv : xv;
    ldout = inside ? ld : 0.0f;
}

// ---------------- fused GEMM3 + spline (R6/R10 form: measured best) ---------
// Wide 128 M x 192 N tile (waves 2x2 of 64x96, acc 4x6), single-buffered
// 2-barrier loop, no swizzle, 4-phase epilogue, __launch_bounds__(256,2).
// R9 LESSON: launch_bounds caps the UNIFIED VGPR+AGPR file; (256,4) spilled
// the 96-reg acc (WRITE_SIZE 9.6->102 MB). Keep (256,2).
// K_eff = 64*(nt+1) exact. 76-78.4us measured across R6/R10/R11 runs.
// This kernel sits at the documented 2-phase-template ceiling (~700 TF):
// occupancy/LDS-volume/barrier-count/HBM-traffic/dbuf/counted-vmcnt all
// proven non-binding (R0-R11). Escape requires the 8-phase schedule -- do
// not attempt without interactive race screening.

__global__ __launch_bounds__(256, 2) void gemm3_spline(
    const uint16_t* __restrict__ A,      // h2: BATCH x HDIM (sorted K)
    const uint16_t* __restrict__ B,      // w2p: NOUTP x HDIM
    const float*    __restrict__ bias,   // b2p: NOUTP
    const float*    __restrict__ x,      // BATCH x N_IN
    float* __restrict__ y,
    float* __restrict__ ldsum)
{
    __shared__ __align__(16) char smem[40960];      // sA 16384 | sB 24576
    uint16_t* sA = (uint16_t*)smem;
    uint16_t* sB = (uint16_t*)(smem + 16384);
    float* ep    = (float*)smem;                    // 32*196*4 = 25088 (alias)

    const int NT  = 16;                             // 3072 / 192
    const int per = 64 * NT;                        // 1024
    const int id  = blockIdx.x;                     // 0..2047
    const int grp = id / per;
    const int rem = id - grp * per;
    const int mt  = grp * 64 + (rem & 63);
    const int nt  = (NT - 1) - (rem >> 6);          // heavy tiles first
    const int bm  = mt << 7;
    const int bn  = nt * 192;

    const int K = HDIM;
    int K_eff = kpref_dev(8 * nt + 7);              // = 64*(nt+1), exact
    K_eff = min(K, (K_eff + 63) & ~63);

    const int tid   = threadIdx.x;
    const int wid   = tid >> 6;
    const int lane  = tid & 63;
    const int wm    = (wid & 1) << 6;               // 0 / 64
    const int wn    = (wid >> 1) * 96;              // 0 / 96
    const int lrow  = lane & 15;
    const int lquad = lane >> 4;

    const f32x4 vzero = {0.0f, 0.0f, 0.0f, 0.0f};
    f32x4 acc[4][6];
#pragma unroll
    for (int i = 0; i < 4; ++i)
#pragma unroll
        for (int j = 0; j < 6; ++j) acc[i][j] = vzero;

    int goffA[4], goffB[6];
#pragma unroll
    for (int t = 0; t < 4; ++t) {
        int c = t * 256 + tid;
        int row = c >> 3, j = c & 7;                // row 0..127
        goffA[t] = row * K * 2 + (j ^ (row & 7)) * 16;
    }
#pragma unroll
    for (int t = 0; t < 6; ++t) {
        int c = t * 256 + tid;
        int row = c >> 3, j = c & 7;                // row 0..191
        goffB[t] = row * K * 2 + (j ^ (row & 7)) * 16;
    }
    const char* gA = (const char*)(A + (size_t)bm * K);
    const char* gB = (const char*)(B + (size_t)bn * K);

    const int octx = lrow & 7;
    const uint16_t* rA = sA + (wm + lrow) * 64;
    const uint16_t* rB = sB + (wn + lrow) * 64;

    for (int k0 = 0; k0 < K_eff; k0 += 64) {
        __syncthreads();
        const int kb = k0 * 2;
#pragma unroll
        for (int t = 0; t < 6; ++t) {
            const int ldsoff = (t * 256 + (wid << 6)) * 16;   // wave-uniform
            if (t < 4)
                async_ld16(gA + goffA[t] + kb, (const char*)sA + ldsoff);
            async_ld16(gB + goffB[t] + kb, (const char*)sB + ldsoff);
        }
        __syncthreads();

#pragma unroll
        for (int ks = 0; ks < 2; ++ks) {
            const int oct = ((ks << 2) | lquad) ^ octx;
            bf16x8 af[4], bfr[6];
#pragma unroll
            for (int i = 0; i < 4; ++i) af[i]  = *(const bf16x8*)(rA + i * 1024 + oct * 8);
#pragma unroll
            for (int j = 0; j < 6; ++j) bfr[j] = *(const bf16x8*)(rB + j * 1024 + oct * 8);
#pragma unroll
            for (int i = 0; i < 4; ++i)
#pragma unroll
                for (int j = 0; j < 6; ++j)
                    acc[i][j] = __builtin_amdgcn_mfma_f32_16x16x32_bf16(
                                    af[i], bfr[j], acc[i][j], 0, 0, 0);
        }
    }

    __syncthreads();                    // staging consumers done; reuse as ep

    // ---- FOUR-PHASE epilogue: 32 rows each --------------------------------
#pragma unroll
    for (int ph = 0; ph < 4; ++ph) {
        if ((wid & 1) == (ph >> 1)) {   // waves owning this 64-row half
#pragma unroll
            for (int ii = 0; ii < 2; ++ii) {
                const int i  = ((ph & 1) << 1) + ii;        // acc row-band
                const int l0 = (ii << 4) + (lquad << 2);    // local row 0..31
#pragma unroll
                for (int j = 0; j < 6; ++j) {
                    const int col = wn + j * 16 + lrow;     // 0..191
                    const float bv = bias[bn + col];
#pragma unroll
                    for (int r = 0; r < 4; ++r)
                        ep[(l0 + r) * 196 + col] = acc[i][j][r] + bv;
                }
            }
        }
        __syncthreads();

        // 256 spline evals: one per thread (32 rows x 8 groups)
        {
            const int row  = tid >> 3;          // 0..31
            const int sg   = tid & 7;           // group within tile (0..7)
            const int grow = bm + (ph << 5) + row;
            const float xv = x[(size_t)grow * N_IN + (8 * nt + sg)];
            float yv, ld;
            spline_eval(ep + row * 196 + sg * OUT_PAD, xv, yv, ld);
            y[(size_t)grow * N_IN + 8 * nt + sg] = yv;

            // sum ld over the 8 lanes sharing this row
            ld += __shfl_xor(ld, 1, 64);
            ld += __shfl_xor(ld, 2, 64);
            ld += __shfl_xor(ld, 4, 64);
            if (sg == 0) atomicAdd(&ldsum[grow], ld);
        }
        if (ph < 3) __syncthreads();    // next phase's writes clobber ep
    }
}

// ---------------- host orchestration ----------------------------------------

extern "C" void kernel_launch(void* const* d_in, const int* in_sizes, int n_in,
                              void* d_out, int out_size, void* d_ws, size_t ws_size,
                              hipStream_t stream)
{
    const float* x     = (const float*)d_in[0];
    const float* ctx   = (const float*)d_in[1];
    const float* ctx_w = (const float*)d_in[2];
    const float* w0    = (const float*)d_in[3];
    const float* b0    = (const float*)d_in[4];
    const float* w1    = (const float*)d_in[5];
    const float* b1    = (const float*)d_in[6];
    const float* w2    = (const float*)d_in[7];
    const float* b2    = (const float*)d_in[8];
    // d_in[9..11] = masks: unused (computed analytically from indices)

    char* ws = (char*)d_ws;
    const size_t XCAT_B = (size_t)BATCH * KCAT * 2;   //   8 MB
    const size_t H_B    = (size_t)BATCH * HDIM * 2;   //  32 MB each
    const size_t WCAT_B = (size_t)HDIM * KCAT * 2;
    const size_t W1_B   = (size_t)HDIM * HDIM * 2;
    const size_t W2P_B  = (size_t)NOUTP * HDIM * 2;

    uint16_t* xcat = (uint16_t*)(ws);
    uint16_t* h1   = (uint16_t*)(ws + XCAT_B);
    uint16_t* h2   = (uint16_t*)(ws + XCAT_B + H_B);
    uint16_t* wcat = (uint16_t*)(ws + XCAT_B + 2 * H_B);
    uint16_t* w1m  = (uint16_t*)(ws + XCAT_B + 2 * H_B + WCAT_B);
    uint16_t* w2p  = (uint16_t*)(ws + XCAT_B + 2 * H_B + WCAT_B + W1_B);
    float*    b0p  = (float*)   (ws + XCAT_B + 2 * H_B + WCAT_B + W1_B + W2P_B);
    float*    b1p  = b0p + HDIM;
    float*    b2p  = b1p + HDIM;

    float* yout  = (float*)d_out;
    float* ldout = yout + (size_t)BATCH * N_IN;

    pack_all<<<9296, 256, 0, stream>>>(x, ctx, ctx_w, w0, b0, w1, b1, w2, b2,
                                       xcat, wcat, w1m, w2p, b0p, b1p, b2p,
                                       ldout);

    const dim3 blk(256);
    gemm1_k<<<dim3(128 * (HDIM / 128)), blk, 0, stream>>>(
        xcat, wcat, b0p, h1, HDIM, KCAT, HDIM / 128);
    gemm2_k<<<dim3(128 * (HDIM / 128)), blk, 0, stream>>>(
        h1, w1m, b1p, h2, HDIM, HDIM, HDIM / 128);
    gemm3_spline<<<dim3(128 * 16), blk, 0, stream>>>(
        h2, w2p, b2p, x, yout, ldout);
}